// Round 19
// baseline (195.944 us; speedup 1.0000x reference)
//
#include <hip/hip_runtime.h>
#include <hip/hip_bf16.h>

typedef unsigned short u16;
typedef unsigned int   u32;

using bf16x8 = __attribute__((ext_vector_type(8))) __bf16;
using f32x4  = __attribute__((ext_vector_type(4))) float;

#define SLOPE 0.22916666666666666f
#define CAP 64      // bucket capacity; deg ~ Poisson(12.8), max over 50k ~ 35
#define FCHUNK 2048 // edges per fill chunk (x8 XCD-group blocks)

static __device__ __forceinline__ u16 f2bf(float f) {
    u32 u = __float_as_uint(f);
    u += 0x7fffu + ((u >> 16) & 1u);   // RNE
    return (u16)(u >> 16);
}
static __device__ __forceinline__ float bf2f(u16 h) {
    return __uint_as_float(((u32)h) << 16);
}

static __device__ __forceinline__ void gload_lds16(const u16* g, u16* l) {
    __builtin_amdgcn_global_load_lds(
        (const __attribute__((address_space(1))) void*)g,
        (__attribute__((address_space(3))) void*)l,
        16, 0, 0);
}

static __device__ __forceinline__ void add8(float* a, uint4 u) {
    a[0] += bf2f((u16)u.x); a[1] += bf2f((u16)(u.x >> 16));
    a[2] += bf2f((u16)u.y); a[3] += bf2f((u16)(u.y >> 16));
    a[4] += bf2f((u16)u.z); a[5] += bf2f((u16)(u.z >> 16));
    a[6] += bf2f((u16)u.w); a[7] += bf2f((u16)(u.w >> 16));
}

// ---------------- fused prep: XCD-partitioned bucket fill + node f2bf + weight convert ----------------
// Fill: blocks with blockIdx%8==g process only edges whose dst is in node-range g.
// Dispatcher round-robins blockIdx%8 -> XCD, so each node's bucket lines are written
// by ONE XCD -> its L2 merges them into full-line writebacks (round-18 win, -12us).
// CHUNK=2048 + int4 dst loads: 4x fewer blocks, better per-XCD L2 retention.
__global__ void k_prep(const int* __restrict__ src, const int* __restrict__ dst,
                       int* __restrict__ deg, int2* __restrict__ se,
                       const float* __restrict__ node, u16* __restrict__ nfb,
                       const float* __restrict__ W1, const float* __restrict__ L1,
                       const float* __restrict__ W2, const float* __restrict__ L2,
                       const float* __restrict__ Wo, u16* __restrict__ T,
                       int E, int N, int n8, int gFill, int gF) {
    int b = blockIdx.x, t = threadIdx.x;
    if (b < gFill) {
        int chunk = b >> 3, g = b & 7;       // blockIdx%8 -> XCD (dispatch round-robin)
        int lo = (int)(((long long)g * N) >> 3);
        int hi = (int)(((long long)(g + 1) * N) >> 3);
        int base = chunk * FCHUNK;
        #pragma unroll
        for (int k = 0; k < FCHUNK / 1024; k++) {
            int i0 = base + k * 1024 + t * 4;
            if (i0 + 4 <= E) {
                int4 d4 = *(const int4*)(dst + i0);
                #pragma unroll
                for (int j = 0; j < 4; j++) {
                    int d = (&d4.x)[j];
                    if (d >= lo && d < hi) {
                        int p = atomicAdd(&deg[d], 1);
                        if (p < CAP) se[(size_t)d * CAP + p] = make_int2(src[i0 + j], i0 + j);
                    }
                }
            } else {
                for (int j = 0; j < 4; j++) {
                    int i = i0 + j;
                    if (i < E) {
                        int d = dst[i];
                        if (d >= lo && d < hi) {
                            int p = atomicAdd(&deg[d], 1);
                            if (p < CAP) se[(size_t)d * CAP + p] = make_int2(src[i], i);
                        }
                    }
                }
            }
        }
    } else if (b < gFill + gF) {
        int i = (b - gFill) * 256 + t;
        if (i < n8) {
            const float4* p = (const float4*)node + (size_t)i * 2;
            float4 a = p[0], c = p[1];
            union { u16 u[8]; uint4 v; } pk;
            pk.u[0] = f2bf(a.x); pk.u[1] = f2bf(a.y); pk.u[2] = f2bf(a.z); pk.u[3] = f2bf(a.w);
            pk.u[4] = f2bf(c.x); pk.u[5] = f2bf(c.y); pk.u[6] = f2bf(c.z); pk.u[7] = f2bf(c.w);
            *((uint4*)nfb + i) = pk.v;
        }
    } else {
        int mb = b - gFill - gF;         // 0..63: 8 matrices x 8 slices
        int m = mb >> 3, chunk = mb & 7;
        const float* S; int rowoff;
        switch (m) {
            case 0: S = W1; rowoff = 0;   break;
            case 1: S = W1; rowoff = 128; break;
            case 2: S = L1; rowoff = 0;   break;
            case 3: S = W2; rowoff = 0;   break;
            case 4: S = W2; rowoff = 128; break;
            case 5: S = L2; rowoff = 0;   break;
            case 6: S = Wo; rowoff = 0;   break;
            default: S = Wo; rowoff = 128; break;
        }
        u16* O = T + m * 16384;
        int j0 = chunk * 2048, j1 = j0 + 2048;
        for (int j = j0 + t; j < j1; j += 256) {
            int c = j >> 7, k = j & 127;
            O[j] = f2bf(S[(rowoff + k) * 128 + c]);   // [col][k] layout
        }
    }
}

// ---------------- fused gather-mean: EF = mean(ef[eid]), A = mean(nfb[src]) ----------------
// measured ~70us (round 8), DRAM-random-row-bound (at floor)
__global__ void k_aggf(const float* __restrict__ ef, const u16* __restrict__ nfb,
                       const int2* __restrict__ se, const int* __restrict__ deg,
                       u16* __restrict__ EF, u16* __restrict__ A, int N) {
    int w = (blockIdx.x * blockDim.x + threadIdx.x) >> 6;
    int lane = threadIdx.x & 63;
    if (w >= N) return;
    int t4 = lane >> 4, qq = lane & 15;
    int d = deg[w];
    int dc = d < CAP ? d : CAP;
    const int2* sp = se + (size_t)w * CAP;
    float e[8] = {0.f, 0.f, 0.f, 0.f, 0.f, 0.f, 0.f, 0.f};
    float n[8] = {0.f, 0.f, 0.f, 0.f, 0.f, 0.f, 0.f, 0.f};
    int i = 0;
    for (; i + 8 <= dc; i += 8) {
        int2 iA = sp[i + t4], iB = sp[i + 4 + t4];
        const float* ra = ef + (size_t)iA.y * 128 + qq * 8;
        const float* rb = ef + (size_t)iB.y * 128 + qq * 8;
        float4 a0 = *(const float4*)ra, a1 = *(const float4*)(ra + 4);
        float4 c0 = *(const float4*)rb, c1 = *(const float4*)(rb + 4);
        uint4 ua = *(const uint4*)(nfb + (size_t)iA.x * 128 + qq * 8);
        uint4 ub = *(const uint4*)(nfb + (size_t)iB.x * 128 + qq * 8);
        e[0] += a0.x + c0.x; e[1] += a0.y + c0.y; e[2] += a0.z + c0.z; e[3] += a0.w + c0.w;
        e[4] += a1.x + c1.x; e[5] += a1.y + c1.y; e[6] += a1.z + c1.z; e[7] += a1.w + c1.w;
        add8(n, ua); add8(n, ub);
    }
    for (; i + 4 <= dc; i += 4) {
        int2 iA = sp[i + t4];
        const float* ra = ef + (size_t)iA.y * 128 + qq * 8;
        float4 a0 = *(const float4*)ra, a1 = *(const float4*)(ra + 4);
        uint4 ua = *(const uint4*)(nfb + (size_t)iA.x * 128 + qq * 8);
        e[0] += a0.x; e[1] += a0.y; e[2] += a0.z; e[3] += a0.w;
        e[4] += a1.x; e[5] += a1.y; e[6] += a1.z; e[7] += a1.w;
        add8(n, ua);
    }
    if (i + t4 < dc) {
        int2 iA = sp[i + t4];
        const float* ra = ef + (size_t)iA.y * 128 + qq * 8;
        float4 a0 = *(const float4*)ra, a1 = *(const float4*)(ra + 4);
        uint4 ua = *(const uint4*)(nfb + (size_t)iA.x * 128 + qq * 8);
        e[0] += a0.x; e[1] += a0.y; e[2] += a0.z; e[3] += a0.w;
        e[4] += a1.x; e[5] += a1.y; e[6] += a1.z; e[7] += a1.w;
        add8(n, ua);
    }
    #pragma unroll
    for (int j = 0; j < 8; j++) {
        e[j] += __shfl_xor(e[j], 16); e[j] += __shfl_xor(e[j], 32);
        n[j] += __shfl_xor(n[j], 16); n[j] += __shfl_xor(n[j], 32);
    }
    float sc = d > 0 ? 1.0f / (float)d : 0.0f;
    if (t4 == 0) {
        union { u16 u[8]; uint4 v; } pk;
        #pragma unroll
        for (int j = 0; j < 8; j++) pk.u[j] = f2bf(e[j] * sc);
        *(uint4*)(EF + (size_t)w * 128 + qq * 8) = pk.v;
    } else if (t4 == 1) {
        union { u16 u[8]; uint4 v; } pk;
        #pragma unroll
        for (int j = 0; j < 8; j++) pk.u[j] = f2bf(n[j] * sc);
        *(uint4*)(A + (size_t)w * 128 + qq * 8) = pk.v;
    }
}

// ---------------- gather-mean of bf16 rows (h1): measured ~9us ----------------
__global__ void k_aggb(const u16* __restrict__ h, const int2* __restrict__ se,
                       const int* __restrict__ deg, u16* __restrict__ out, int N) {
    int w = (blockIdx.x * blockDim.x + threadIdx.x) >> 6;
    int lane = threadIdx.x & 63;
    if (w >= N) return;
    int quarter = lane >> 4, q = lane & 15;
    int d = deg[w];
    int dc = d < CAP ? d : CAP;
    const int2* sp = se + (size_t)w * CAP;
    float a[8] = {0.f, 0.f, 0.f, 0.f, 0.f, 0.f, 0.f, 0.f};
    int i = 0;
    for (; i + 8 <= dc; i += 8) {
        int eA = sp[i + quarter].x, eB = sp[i + 4 + quarter].x;
        uint4 uA = *(const uint4*)(h + (size_t)eA * 128 + q * 8);
        uint4 uB = *(const uint4*)(h + (size_t)eB * 128 + q * 8);
        add8(a, uA); add8(a, uB);
    }
    for (; i + 4 <= dc; i += 4) {
        int eA = sp[i + quarter].x;
        uint4 uA = *(const uint4*)(h + (size_t)eA * 128 + q * 8);
        add8(a, uA);
    }
    if (i + quarter < dc) {
        int eA = sp[i + quarter].x;
        uint4 uA = *(const uint4*)(h + (size_t)eA * 128 + q * 8);
        add8(a, uA);
    }
    #pragma unroll
    for (int j = 0; j < 8; j++) {
        a[j] += __shfl_xor(a[j], 32);
        a[j] += __shfl_xor(a[j], 16);
    }
    if (quarter == 0) {
        float sc = d > 0 ? 1.0f / (float)d : 0.0f;
        union { u16 u[8]; uint4 v; } pk;
        #pragma unroll
        for (int j = 0; j < 8; j++) pk.u[j] = f2bf(a[j] * sc);
        *(uint4*)(out + (size_t)w * 128 + q * 8) = pk.v;
    }
}

// ---------------- GEMM helpers (BM=128, 512 threads, 4x2 waves) ----------------
#define STAGE_X128(LBUF, GPTR)                                                      \
    {                                                                               \
        _Pragma("unroll")                                                           \
        for (int i_ = 0; i_ < 4; i_++) {                                            \
            int id_ = t + i_ * 512;                                                 \
            int r_ = id_ >> 4, c16_ = id_ & 15;                                     \
            int rg_ = row0 + r_; if (rg_ >= N) rg_ = N - 1;                         \
            gload_lds16((GPTR) + (size_t)rg_ * 128 + ((c16_ ^ (r_ & 15)) << 3),     \
                        (LBUF) + id_ * 8);                                          \
        }                                                                           \
    }
#define STAGE_W512(GPTR)                                                            \
    {                                                                               \
        _Pragma("unroll")                                                           \
        for (int i_ = 0; i_ < 4; i_++) {                                            \
            int id_ = t + i_ * 512;                                                 \
            int cc_ = id_ >> 4, c16_ = id_ & 15;                                    \
            gload_lds16((GPTR) + cc_ * 128 + ((c16_ ^ (cc_ & 15)) << 3),            \
                        Wl + id_ * 8);                                              \
        }                                                                           \
    }
#define COMPUTE(LBUF)                                                               \
    {                                                                               \
        _Pragma("unroll")                                                           \
        for (int ks_ = 0; ks_ < 4; ks_++) {                                         \
            bf16x8 af_[2], bf_[4];                                                  \
            _Pragma("unroll")                                                       \
            for (int h_ = 0; h_ < 2; h_++) {                                        \
                int r_ = wr * 32 + h_ * 16 + lanelo;                                \
                int ch_ = (ks_ * 4 + lanehi) ^ (r_ & 15);                           \
                af_[h_] = *(const bf16x8*)((LBUF) + r_ * 128 + ch_ * 8);            \
            }                                                                       \
            _Pragma("unroll")                                                       \
            for (int g_ = 0; g_ < 4; g_++) {                                        \
                int cc_ = wc * 64 + g_ * 16 + lanelo;                               \
                int ch_ = (ks_ * 4 + lanehi) ^ (cc_ & 15);                          \
                bf_[g_] = *(const bf16x8*)(Wl + cc_ * 128 + ch_ * 8);               \
            }                                                                       \
            _Pragma("unroll")                                                       \
            for (int h_ = 0; h_ < 2; h_++)                                          \
                _Pragma("unroll")                                                   \
                for (int g_ = 0; g_ < 4; g_++)                                      \
                    acc[h_][g_] = __builtin_amdgcn_mfma_f32_16x16x32_bf16(          \
                        af_[h_], bf_[g_], acc[h_][g_], 0, 0, 0);                    \
        }                                                                           \
    }

// ---------------- 3-segment GEMM (measured ~11.5us each) ----------------
__global__ __launch_bounds__(512, 4) void k_gemm3s(
    const u16* __restrict__ X0, const u16* __restrict__ X1, const u16* __restrict__ X2,
    const u16* __restrict__ T0, const u16* __restrict__ T1, const u16* __restrict__ T2,
    const float* __restrict__ bm, const int* __restrict__ deg,
    const float* __restrict__ ba, u16* __restrict__ outp, int N) {

    __shared__ u16 XB[128 * 128];
    __shared__ u16 Wl[128 * 128];

    int t = threadIdx.x, lane = t & 63, wid = t >> 6;
    int lanelo = lane & 15, lanehi = lane >> 4;
    int wr = wid >> 1, wc = wid & 1;
    int row0 = blockIdx.x * 128;

    f32x4 acc[2][4];
    #pragma unroll
    for (int h = 0; h < 2; h++)
        #pragma unroll
        for (int g = 0; g < 4; g++) acc[h][g] = (f32x4){0.f, 0.f, 0.f, 0.f};

    STAGE_X128(XB, X0);
    STAGE_W512(T0);
    __syncthreads();
    COMPUTE(XB);
    __syncthreads();
    STAGE_X128(XB, X1);
    STAGE_W512(T1);
    __syncthreads();
    COMPUTE(XB);
    __syncthreads();
    STAGE_X128(XB, X2);
    STAGE_W512(T2);
    __syncthreads();
    COMPUTE(XB);

    #pragma unroll
    for (int h = 0; h < 2; h++) {
        #pragma unroll
        for (int r = 0; r < 4; r++) {
            int rowt = wr * 32 + h * 16 + lanehi * 4 + r;
            int rg = row0 + rowt;
            if (rg >= N) continue;
            float m = (deg[rg] > 0) ? 1.f : 0.f;
            #pragma unroll
            for (int g = 0; g < 4; g++) {
                int col = wc * 64 + g * 16 + lanelo;
                float v = acc[h][g][r] + ba[col] + m * bm[col];
                v = (v >= 0.f) ? v : v * SLOPE;
                outp[(size_t)rg * 128 + col] = f2bf(v);
            }
        }
    }
}

// ---------------- 2-segment output GEMM (f32) ----------------
__global__ __launch_bounds__(512, 4) void k_gemmo(
    const u16* __restrict__ X0, const u16* __restrict__ X1,
    const u16* __restrict__ T0, const u16* __restrict__ T1,
    const float* __restrict__ ba, float* __restrict__ outp, int N) {

    __shared__ u16 XB[128 * 128];
    __shared__ u16 Wl[128 * 128];

    int t = threadIdx.x, lane = t & 63, wid = t >> 6;
    int lanelo = lane & 15, lanehi = lane >> 4;
    int wr = wid >> 1, wc = wid & 1;
    int row0 = blockIdx.x * 128;

    f32x4 acc[2][4];
    #pragma unroll
    for (int h = 0; h < 2; h++)
        #pragma unroll
        for (int g = 0; g < 4; g++) acc[h][g] = (f32x4){0.f, 0.f, 0.f, 0.f};

    STAGE_X128(XB, X0);
    STAGE_W512(T0);
    __syncthreads();
    COMPUTE(XB);
    __syncthreads();
    STAGE_X128(XB, X1);
    STAGE_W512(T1);
    __syncthreads();
    COMPUTE(XB);

    #pragma unroll
    for (int h = 0; h < 2; h++) {
        #pragma unroll
        for (int r = 0; r < 4; r++) {
            int rowt = wr * 32 + h * 16 + lanehi * 4 + r;
            int rg = row0 + rowt;
            if (rg >= N) continue;
            #pragma unroll
            for (int g = 0; g < 4; g++) {
                int col = wc * 64 + g * 16 + lanelo;
                outp[(size_t)rg * 128 + col] = acc[h][g][r] + ba[col];
            }
        }
    }
}

// ---------------- launch ----------------

extern "C" void kernel_launch(void* const* d_in, const int* in_sizes, int n_in,
                              void* d_out, int out_size, void* d_ws, size_t ws_size,
                              hipStream_t stream) {
    const float* node = (const float*)d_in[0];
    const float* ef   = (const float*)d_in[1];
    const int*   src  = (const int*)d_in[2];
    const int*   dst  = (const int*)d_in[3];
    const float* W1   = (const float*)d_in[4];
    const float* b1   = (const float*)d_in[5];
    const float* L1   = (const float*)d_in[6];
    const float* lb1  = (const float*)d_in[7];
    const float* W2   = (const float*)d_in[8];
    const float* b2   = (const float*)d_in[9];
    const float* L2   = (const float*)d_in[10];
    const float* lb2  = (const float*)d_in[11];
    const float* Wo   = (const float*)d_in[12];
    const float* bo   = (const float*)d_in[13];
    int N = in_sizes[0] / 128;
    int E = in_sizes[2];

    char* ws = (char*)d_ws;
    size_t o = 0;
    auto alloc = [&](size_t bytes) {
        void* p = ws + o;
        o = (o + bytes + 511) & ~(size_t)511;
        return p;
    };
    int*  deg = (int*)alloc((size_t)N * 4);
    int2* se  = (int2*)alloc((size_t)N * CAP * 8);
    u16*  T   = (u16*)alloc((size_t)8 * 16384 * 2);
    u16*  nfb = (u16*)alloc((size_t)N * 128 * 2);
    u16*  EF  = (u16*)alloc((size_t)N * 128 * 2);
    u16*  A   = (u16*)alloc((size_t)N * 128 * 2);
    u16*  h1  = (u16*)alloc((size_t)N * 128 * 2);
    u16*  h2  = (u16*)alloc((size_t)N * 128 * 2);

    hipMemsetAsync(deg, 0, (size_t)N * 4, stream);

    int nChunk = (E + FCHUNK - 1) / FCHUNK;
    int gFill = nChunk * 8;              // 8 XCD-groups per chunk
    int n8 = N * 128 / 8;
    int gF = (n8 + 255) / 256;
    k_prep<<<gFill + gF + 64, 256, 0, stream>>>(src, dst, deg, se, node, nfb,
                                                W1, L1, W2, L2, Wo, T,
                                                E, N, n8, gFill, gF);

    int gA = (N + 3) / 4;
    k_aggf<<<gA, 256, 0, stream>>>(ef, nfb, se, deg, EF, A, N);

    int gb = (N + 127) / 128;
    // h1 = leaky(A@W1a + EF@W1b + nfb@L1 + mask*b1 + lb1)
    k_gemm3s<<<gb, 512, 0, stream>>>(A, EF, nfb, T, T + 16384, T + 2 * 16384,
                                     b1, deg, lb1, h1, N);
    // A = mean(h1[src])
    k_aggb<<<gA, 256, 0, stream>>>(h1, se, deg, A, N);
    // h2 = leaky(A@W2a + EF@W2b + h1@L2 + mask*b2 + lb2)
    k_gemm3s<<<gb, 512, 0, stream>>>(A, EF, h1, T + 3 * 16384, T + 4 * 16384, T + 5 * 16384,
                                     b2, deg, lb2, h2, N);
    // out = h1@WoA + h2@WoB + bo  (f32)
    k_gemmo<<<gb, 512, 0, stream>>>(h1, h2, T + 6 * 16384, T + 7 * 16384,
                                    bo, (float*)d_out, N);
}